// Round 12
// baseline (113.467 us; speedup 1.0000x reference)
//
#include <hip/hip_runtime.h>

// ---------------------------------------------------------------------------
// MultiHeadAttentionWindow: B=8 K=4000 D=256 H=8 DQ=DV=32 WIN=200 PAD=50 STEP=100
// Pipeline: prep_weights; gemm256<0/1/2> (separate q/k/v projections);
//           fill_edges; attn_win (chunked-E); gemm256<3> (output).
// Round-12: BISECTION — GEMM restored to the EXACT round-3 kernel (the
//   fastest measured: ~15.4 us/GEMM by total-time accounting), separate
//   launches per mode. r11's z-merge + gload-B ran 23 us/GEMM; this isolates
//   which delta caused it. Attention stays the r5 chunked-E version (~14 us).
// ---------------------------------------------------------------------------

typedef __bf16 bf16_t;
typedef __bf16 bf16x8 __attribute__((ext_vector_type(8)));
typedef float  f32x4  __attribute__((ext_vector_type(4)));

#define MFMA16(a, b, c) __builtin_amdgcn_mfma_f32_16x16x32_bf16((a), (b), (c), 0, 0, 0)

static __device__ __forceinline__ bf16x8 cvt8(float4 a, float4 b) {
  bf16x8 r;
  r[0] = (bf16_t)a.x; r[1] = (bf16_t)a.y; r[2] = (bf16_t)a.z; r[3] = (bf16_t)a.w;
  r[4] = (bf16_t)b.x; r[5] = (bf16_t)b.y; r[6] = (bf16_t)b.z; r[7] = (bf16_t)b.w;
  return r;
}

static __device__ __forceinline__ unsigned short bbits(bf16_t v) {
  union { bf16_t b; unsigned short u; } c; c.b = v; return c.u;
}

// ---- weight transpose + bf16 convert: Wt[n][k] = bf16(W[k][n]), 4 matrices ----
__global__ __launch_bounds__(256)
void prep_weights(const float* __restrict__ Wq, const float* __restrict__ Wk,
                  const float* __restrict__ Wv, const float* __restrict__ Wo,
                  bf16_t* __restrict__ wt) {
  const int mat  = blockIdx.x >> 6;
  const int tile = blockIdx.x & 63;
  const int kt = (tile >> 3) * 32, nt = (tile & 7) * 32;
  const float* W = (mat == 0) ? Wq : (mat == 1) ? Wk : (mat == 2) ? Wv : Wo;
  __shared__ float t[32][33];
  const int tx = threadIdx.x & 31, ty = threadIdx.x >> 5;  // ty 0..7
#pragma unroll
  for (int i = 0; i < 32; i += 8)
    t[ty + i][tx] = W[(size_t)(kt + ty + i) * 256 + nt + tx];
  __syncthreads();
  bf16_t* dst = wt + (size_t)mat * 65536;
#pragma unroll
  for (int i = 0; i < 32; i += 8)
    dst[(size_t)(nt + ty + i) * 256 + kt + tx] = (bf16_t)t[tx][ty + i];
}

// ---- GEMM: [M x 256] x [256 x 256] + bias, 128x128 tile, 4 waves ----
// EXACT round-3 kernel (fastest measured). MODE 0: fp32->bf16 qb (*oscale);
// MODE 1: fp32->bf16 kb rows b*4064+t+50; MODE 2: fp32->bf16 vt transposed;
// MODE 3: bf16 ao -> fp32 out.
template <int MODE>
__global__ __launch_bounds__(256)
void gemm256(const void* __restrict__ Xv, const bf16_t* __restrict__ Wt,
             const float* __restrict__ bias, void* __restrict__ Out, int M,
             float oscale = 1.f) {
  constexpr bool INB = (MODE == 3);
  const int m0 = blockIdx.x * 128;
  const int n0 = blockIdx.y * 128;
  __shared__ bf16_t la[128 * 40];  // stride 40 bf16 = 80 B rows (16B-aligned)
  __shared__ bf16_t lb[128 * 40];
  const int tid  = threadIdx.x;
  const int lane = tid & 63;
  const int wr   = ((tid >> 7) & 1) * 64;  // wave row offset
  const int wc   = ((tid >> 6) & 1) * 64;  // wave col offset
  const int lo   = lane & 15, hi = lane >> 4;
  const int arow = tid >> 1;           // 0..127
  const int acol = (tid & 1) * 16;     // 0 or 16
  int ar = m0 + arow; if (ar >= M) ar = M - 1;   // clamped staging row

  f32x4 acc[4][4] = {};

  for (int kk = 0; kk < 256; kk += 32) {
    if constexpr (!INB) {
      const float* X = (const float*)Xv + (size_t)ar * 256 + kk + acol;
      float4 x0 = ((const float4*)X)[0];
      float4 x1 = ((const float4*)X)[1];
      float4 x2 = ((const float4*)X)[2];
      float4 x3 = ((const float4*)X)[3];
      *(bf16x8*)&la[arow * 40 + acol]     = cvt8(x0, x1);
      *(bf16x8*)&la[arow * 40 + acol + 8] = cvt8(x2, x3);
    } else {
      const bf16_t* X = (const bf16_t*)Xv + (size_t)ar * 256 + kk + acol;
      *(bf16x8*)&la[arow * 40 + acol]     = ((const bf16x8*)X)[0];
      *(bf16x8*)&la[arow * 40 + acol + 8] = ((const bf16x8*)X)[1];
    }
    {
      const bf16_t* Wp = Wt + (size_t)(n0 + arow) * 256 + kk + acol;
      *(bf16x8*)&lb[arow * 40 + acol]     = ((const bf16x8*)Wp)[0];
      *(bf16x8*)&lb[arow * 40 + acol + 8] = ((const bf16x8*)Wp)[1];
    }
    __syncthreads();

    bf16x8 af[4], bfv[4];
#pragma unroll
    for (int mi = 0; mi < 4; ++mi)
      af[mi] = *(const bf16x8*)&la[(wr + mi * 16 + lo) * 40 + hi * 8];
#pragma unroll
    for (int ni = 0; ni < 4; ++ni)
      bfv[ni] = *(const bf16x8*)&lb[(wc + ni * 16 + lo) * 40 + hi * 8];
#pragma unroll
    for (int mi = 0; mi < 4; ++mi)
#pragma unroll
      for (int ni = 0; ni < 4; ++ni)
        acc[mi][ni] = MFMA16(af[mi], bfv[ni], acc[mi][ni]);
    __syncthreads();
  }

  // epilogue: C/D layout col = lane&15, row = (lane>>4)*4 + r  [m89-verified]
#pragma unroll
  for (int mi = 0; mi < 4; ++mi)
#pragma unroll
    for (int ni = 0; ni < 4; ++ni) {
      const int n   = n0 + wc + ni * 16 + lo;
      const float bia = bias[n];
      const int mb  = m0 + wr + mi * 16 + hi * 4;  // 4-aligned
      if (mb >= M) continue;                       // M % 4 == 0
      if constexpr (MODE == 0) {
        bf16_t* O = (bf16_t*)Out;
#pragma unroll
        for (int r = 0; r < 4; ++r)
          O[(size_t)(mb + r) * 256 + n] = (bf16_t)((acc[mi][ni][r] + bia) * oscale);
      } else if constexpr (MODE == 1) {
        const int b = mb / 4000, t = mb - b * 4000;
        bf16_t* O = (bf16_t*)Out;
#pragma unroll
        for (int r = 0; r < 4; ++r)
          O[((size_t)b * 4064 + t + 50 + r) * 256 + n] = (bf16_t)(acc[mi][ni][r] + bia);
      } else if constexpr (MODE == 2) {
        const int b = mb / 4000, t = mb - b * 4000;
        const int h = n >> 5, dv = n & 31;
        bf16_t* O = (bf16_t*)Out + ((size_t)((b * 8 + h) * 32 + dv)) * 4064 + t + 50;
        unsigned short e0 = bbits((bf16_t)(acc[mi][ni][0] + bia));
        unsigned short e1 = bbits((bf16_t)(acc[mi][ni][1] + bia));
        unsigned short e2 = bbits((bf16_t)(acc[mi][ni][2] + bia));
        unsigned short e3 = bbits((bf16_t)(acc[mi][ni][3] + bia));
        unsigned* O32 = (unsigned*)O;  // (t+50) even -> 4B aligned
        O32[0] = (unsigned)e0 | ((unsigned)e1 << 16);
        O32[1] = (unsigned)e2 | ((unsigned)e3 << 16);
      } else {
        float* O = (float*)Out;
#pragma unroll
        for (int r = 0; r < 4; ++r)
          O[(size_t)(mb + r) * 256 + n] = acc[mi][ni][r] + bia;
      }
    }
}

// ---- fill replicate-pad edges + zero tails for kb and vt (nb batches) ----
__global__ void fill_edges(bf16_t* __restrict__ kb, bf16_t* __restrict__ vt, int nb) {
  const int idx = blockIdx.x * 256 + threadIdx.x;
  const int kcnt = nb * 64 * 256;
  if (idx < kcnt) {                    // kb: [nb][4064][256]
    const int b  = idx >> 14;
    const int pp = (idx >> 8) & 63;    // 0..63
    const int nn = idx & 255;
    const int p  = (pp < 50) ? pp : pp + 4000;   // [0,50) and [4050,4064)
    bf16_t v = (pp < 50) ? kb[((size_t)b * 4064 + 50) * 256 + nn] : (bf16_t)0.f;
    kb[((size_t)b * 4064 + p) * 256 + nn] = v;
  } else {                             // vt: [nb*8][32][4064]
    const int j  = idx - kcnt;
    const int bh = j >> 11;
    const int dv = (j >> 6) & 31;
    const int pp = j & 63;
    const int p  = (pp < 50) ? pp : pp + 4000;
    bf16_t v = (pp < 50) ? vt[((size_t)bh * 32 + dv) * 4064 + 50] : (bf16_t)0.f;
    vt[((size_t)bh * 32 + dv) * 4064 + p] = v;
  }
}

// ---- windowed attention: one block per (b',h,window), 7 waves = 7 row-strips ----
// Chunked: per 32-col chunk {2x QK MFMA -> exp -> 16x32 LDS bounce -> PV 3 MFMA}.
// No cross-lane ops, no barriers; denom via E@ones; normalize after PV.
__global__ __launch_bounds__(448)
void attn_win(const bf16_t* __restrict__ qb, const bf16_t* __restrict__ kb,
              const bf16_t* __restrict__ vt, bf16_t* __restrict__ ao) {
  const int blk = blockIdx.x;
  const int n = blk % 40;
  const int h = (blk / 40) & 7;
  const int b = blk / 320;
  const int wv = threadIdx.x >> 6;     // strip 0..6, rows i in [50+16wv, 66+16wv)
  const int lane = threadIdx.x & 63;
  const int lo = lane & 15, hi = lane >> 4;

  __shared__ __align__(16) bf16_t E[7][16][40];  // per-wave 16x32 chunk (pad 40)

  const int i0 = 50 + 16 * wv;
  int jtmax = (65 + 16 * wv) >> 4;     // last 16-tile with any unmasked element
  if (jtmax > 9) jtmax = 9;
  const int reach = jtmax * 16 + 16;

  // Q fragment (pre-scaled by 1/sqrt(200)): row lo -> token t = n*100+16wv+lo
  int tq = n * 100 + 16 * wv + lo;
  if (tq > 3999) tq = 3999;            // rows i>=150 are discarded at store
  const bf16x8 qf = *(const bf16x8*)&qb[((size_t)b * 4000 + tq) * 256 + h * 32 + hi * 8];

  const f32x4 zero = {0.f, 0.f, 0.f, 0.f};
  bf16x8 onesf;
#pragma unroll
  for (int u = 0; u < 8; ++u) onesf[u] = (bf16_t)1.0f;

  f32x4 o0 = zero, o1 = zero, sm = zero;
  const size_t vbase = ((size_t)((b * 8 + h) * 32)) * 4064 + n * 100;
  const size_t kbase = ((size_t)(b * 4064 + n * 100)) * 256 + h * 32 + hi * 8;
  const int dbase = i0 + hi * 4 - lo;  // d = dbase + r - 16*jt

#pragma unroll
  for (int kt = 0; kt < 5; ++kt) if (kt * 32 < reach) {
    // two score tiles -> E chunk [16][32]
#pragma unroll
    for (int half = 0; half < 2; ++half) {
      const int jt = kt * 2 + half;
      if (jt <= jtmax) {
        const bf16x8 kf = *(const bf16x8*)&kb[kbase + (size_t)(jt * 16 + lo) * 256];
        const f32x4 s = MFMA16(qf, kf, zero);
#pragma unroll
        for (int r = 0; r < 4; ++r) {
          const int d = dbase + r - jt * 16;
          const float df = (float)d;
          float c = __builtin_amdgcn_rcpf(__builtin_fmaf(0.25f * df, df, 1.f));
          c = (d == 0) ? 0.f : c;      // eye-mask: diagonal score -> 0 -> e=1
          float e = __expf(s[r] * c);
          e = (d < 0) ? 0.f : e;       // causal mask
          E[wv][hi * 4 + r][half * 16 + lo] = (bf16_t)e;
        }
      } else {
#pragma unroll
        for (int r = 0; r < 4; ++r)
          E[wv][hi * 4 + r][half * 16 + lo] = (bf16_t)0.f;
      }
    }
    // PV + denom for this 32-col chunk (wave-private LDS, in-order DS)
    const bf16x8 pf = *(const bf16x8*)&E[wv][lo][hi * 8];
    const bf16x8 v0 = *(const bf16x8*)&vt[vbase + (size_t)lo * 4064 + kt * 32 + hi * 8];
    const bf16x8 v1 = *(const bf16x8*)&vt[vbase + (size_t)(16 + lo) * 4064 + kt * 32 + hi * 8];
    o0 = MFMA16(pf, v0, o0);
    o1 = MFMA16(pf, v1, o1);
    sm = MFMA16(pf, onesf, sm);
  }

  // store central rows (i in [50,150)): out = o * rcp(rowsum); rowsum >= 1
#pragma unroll
  for (int r = 0; r < 4; ++r) {
    const int i = i0 + hi * 4 + r;
    if (i < 150) {
      const float ri = __builtin_amdgcn_rcpf(sm[r]);
      const int t = n * 100 + i - 50;
      bf16_t* op = &ao[((size_t)b * 4000 + t) * 256 + h * 32];
      op[lo]      = (bf16_t)(o0[r] * ri);
      op[16 + lo] = (bf16_t)(o1[r] * ri);
    }
  }
}

// ---------------------------------------------------------------------------
extern "C" void kernel_launch(void* const* d_in, const int* in_sizes, int n_in,
                              void* d_out, int out_size, void* d_ws, size_t ws_size,
                              hipStream_t stream) {
  (void)in_sizes; (void)n_in; (void)out_size;
  const float* query = (const float*)d_in[0];
  const float* key   = (const float*)d_in[1];
  const float* value = (const float*)d_in[2];
  const float* Wq = (const float*)d_in[3];
  const float* bq = (const float*)d_in[4];
  const float* Wk = (const float*)d_in[5];
  const float* bk = (const float*)d_in[6];
  const float* Wv = (const float*)d_in[7];
  const float* bv = (const float*)d_in[8];
  const float* Wo = (const float*)d_in[9];
  const float* bo = (const float*)d_in[10];

  // pick largest batch chunk bc that fits ws_size (ws=256MiB -> bc=8):
  // bytes(bc) = 524288 (wt) + bc * 8,257,536 (qb+kb+vt+ao per batch)
  int bc = 8;
  while (bc > 1 && 524288ull + (unsigned long long)bc * 8257536ull > (unsigned long long)ws_size)
    bc >>= 1;

  bf16_t* wt = (bf16_t*)d_ws;                           // 4 * 65536
  bf16_t* qb = wt + 4 * 65536;                          // bc*4000*256
  bf16_t* kb = qb + (size_t)bc * 4000 * 256;            // bc*4064*256
  bf16_t* vt = kb + (size_t)bc * 4064 * 256;            // bc*8*32*4064
  bf16_t* ao = vt + (size_t)bc * 8 * 32 * 4064;         // bc*4000*256

  prep_weights<<<256, 256, 0, stream>>>(Wq, Wk, Wv, Wo, wt);

  const float qscale = 0.07071067811865475f;  // 1/sqrt(200) folded into qb

  for (int b0 = 0; b0 < 8; b0 += bc) {
    const int M = bc * 4000;
    const int mblk = (M + 127) / 128;
    const float* qx = query + (size_t)b0 * 4000 * 256;
    const float* kx = key   + (size_t)b0 * 4000 * 256;
    const float* vx = value + (size_t)b0 * 4000 * 256;
    float* ox = (float*)d_out + (size_t)b0 * 4000 * 256;

    gemm256<0><<<dim3(mblk, 2), 256, 0, stream>>>(qx, wt + 0 * 65536, bq, qb, M, qscale);
    gemm256<1><<<dim3(mblk, 2), 256, 0, stream>>>(kx, wt + 1 * 65536, bk, kb, M, 1.f);
    gemm256<2><<<dim3(mblk, 2), 256, 0, stream>>>(vx, wt + 2 * 65536, bv, vt, M, 1.f);
    fill_edges<<<bc * 128, 256, 0, stream>>>(kb, vt, bc);
    attn_win<<<bc * 320, 448, 0, stream>>>(qb, kb, vt, ao);
    gemm256<3><<<dim3(mblk, 2), 256, 0, stream>>>(ao, wt + 3 * 65536, bo, ox, M, 1.f);
  }
}

// Round 13
// 94.288 us; speedup vs baseline: 1.2034x; 1.2034x over previous
//
#include <hip/hip_runtime.h>

// ---------------------------------------------------------------------------
// MultiHeadAttentionWindow: B=8 K=4000 D=256 H=8 DQ=DV=32 WIN=200 PAD=50 STEP=100
// Pipeline: prep_weights; proj_gemm (merged q/k/v, grid.y=mode); fill_edges;
//           attn_win (chunked-E); out_gemm.
// Round-13: base = r10 (best, 94.75us). ONE delta: K-loop staging pipelined
//   with T3/T4-minimum 2-phase: LDS double-buffer + issue next tile's
//   global_load_lds BEFORE computing current + counted s_waitcnt vmcnt(6)
//   + raw s_barrier (no vmcnt(0) drain — the r3..r12 GEMMs all drained
//   every iter, which is why they were all stuck at ~23us vs 8.7us floor).
// ---------------------------------------------------------------------------

typedef __bf16 bf16_t;
typedef __bf16 bf16x8 __attribute__((ext_vector_type(8)));
typedef float  f32x4  __attribute__((ext_vector_type(4)));

#define MFMA16(a, b, c) __builtin_amdgcn_mfma_f32_16x16x32_bf16((a), (b), (c), 0, 0, 0)

typedef __attribute__((address_space(1))) const unsigned char gas_u8;
typedef __attribute__((address_space(3))) unsigned char las_u8;

static __device__ __forceinline__ void gload16(const void* g, void* l) {
  __builtin_amdgcn_global_load_lds((gas_u8*)g, (las_u8*)l, 16, 0, 0);
}

static __device__ __forceinline__ bf16x8 cvt8(float4 a, float4 b) {
  bf16x8 r;
  r[0] = (bf16_t)a.x; r[1] = (bf16_t)a.y; r[2] = (bf16_t)a.z; r[3] = (bf16_t)a.w;
  r[4] = (bf16_t)b.x; r[5] = (bf16_t)b.y; r[6] = (bf16_t)b.z; r[7] = (bf16_t)b.w;
  return r;
}

static __device__ __forceinline__ unsigned short bbits(bf16_t v) {
  union { bf16_t b; unsigned short u; } c; c.b = v; return c.u;
}

// ---- weight transpose + bf16 convert: Wt[n][k] = bf16(W[k][n]), 4 matrices ----
__global__ __launch_bounds__(256)
void prep_weights(const float* __restrict__ Wq, const float* __restrict__ Wk,
                  const float* __restrict__ Wv, const float* __restrict__ Wo,
                  bf16_t* __restrict__ wt) {
  const int mat  = blockIdx.x >> 6;
  const int tile = blockIdx.x & 63;
  const int kt = (tile >> 3) * 32, nt = (tile & 7) * 32;
  const float* W = (mat == 0) ? Wq : (mat == 1) ? Wk : (mat == 2) ? Wv : Wo;
  __shared__ float t[32][33];
  const int tx = threadIdx.x & 31, ty = threadIdx.x >> 5;  // ty 0..7
#pragma unroll
  for (int i = 0; i < 32; i += 8)
    t[ty + i][tx] = W[(size_t)(kt + ty + i) * 256 + nt + tx];
  __syncthreads();
  bf16_t* dst = wt + (size_t)mat * 65536;
#pragma unroll
  for (int i = 0; i < 32; i += 8)
    dst[(size_t)(nt + ty + i) * 256 + kt + tx] = (bf16_t)t[tx][ty + i];
}

// ---- merged projection GEMM: [M x 256] x [256 x 256] + bias ----
// grid (mblk, 3); mode = blockIdx.y. Block: 64 rows x 256 cols, 4 waves;
// wave w = rows 0..63 x cols [w*64, w*64+64). Double-buffered pipelined K-loop.
__global__ __launch_bounds__(256)
void proj_gemm(const float* __restrict__ qx, const float* __restrict__ kx,
               const float* __restrict__ vx, const bf16_t* __restrict__ wt,
               const float* __restrict__ bq, const float* __restrict__ bk,
               const float* __restrict__ bv,
               bf16_t* __restrict__ qb, bf16_t* __restrict__ kb,
               bf16_t* __restrict__ vt, int M, float qscale) {
  const int mode = blockIdx.y;
  const float* X    = (mode == 0) ? qx : (mode == 1) ? kx : vx;
  const float* bias = (mode == 0) ? bq : (mode == 1) ? bk : bv;
  const bf16_t* W   = wt + (size_t)mode * 65536;

  // dbuf: [2] x { A 8KB (512 x 16B fp32 slots) + B 16KB (1024 x 16B bf16) }
  __shared__ __align__(16) char lds[2 * 24576];

  const int tid  = threadIdx.x;
  const int lane = tid & 63;
  const int w    = tid >> 6;        // wave 0..3 (n-slice wn = w*64)
  const int lo   = lane & 15, hi = lane >> 4;
  const int m0   = blockIdx.x * 64;

  // A staging: j in {0,1}: slot s=(w*2+j)*64+lane; row=s>>3, f=s&7,
  // holds fp32-chunk c4 = f ^ (row&7) of row. src += kk*128B per K-tile.
  const float* asrc[2];
  int aoff[2];
#pragma unroll
  for (int j = 0; j < 2; ++j) {
    const int s = (w * 2 + j) * 64 + lane;
    const int row = s >> 3, f = s & 7;
    const int ar = (m0 + row < M) ? (m0 + row) : (M - 1);
    asrc[j] = X + (size_t)ar * 256 + ((f ^ (row & 7)) << 2);
    aoff[j] = (w * 2 + j) * 1024;
  }
  // B staging: j in {0..3}: slot s=(w*4+j)*64+lane; row=s>>2, ch=s&3 (linear)
  const bf16_t* bsrc[4];
  int boff[4];
#pragma unroll
  for (int j = 0; j < 4; ++j) {
    const int s = (w * 4 + j) * 64 + lane;
    bsrc[j] = W + (size_t)(s >> 2) * 256 + ((s & 3) << 3);
    boff[j] = 8192 + (w * 4 + j) * 1024;
  }
  // fragment read offsets (within a buffer)
  int abase[4], bbase[4];
#pragma unroll
  for (int mi = 0; mi < 4; ++mi)
    abase[mi] = (((mi * 16 + lo) << 3) + ((2 * hi) ^ (lo & 7))) << 4;
#pragma unroll
  for (int ni = 0; ni < 4; ++ni)
    bbase[ni] = 8192 + (w * 64 + ni * 16 + lo) * 64 + hi * 16;

  f32x4 acc[4][4] = {};

  // prologue: stage tile 0 into buffer 0
#pragma unroll
  for (int j = 0; j < 2; ++j) gload16(asrc[j], lds + aoff[j]);
#pragma unroll
  for (int j = 0; j < 4; ++j) gload16(bsrc[j], lds + boff[j]);

  for (int t = 0; t < 8; ++t) {
    const int cur = (t & 1) * 24576;
    if (t < 7) {                     // issue next tile into other buffer
      const int nxt = ((t + 1) & 1) * 24576;
#pragma unroll
      for (int j = 0; j < 2; ++j) gload16(asrc[j] + (t + 1) * 32, lds + nxt + aoff[j]);
#pragma unroll
      for (int j = 0; j < 4; ++j) gload16(bsrc[j] + (t + 1) * 32, lds + nxt + boff[j]);
      asm volatile("s_waitcnt vmcnt(6)" ::: "memory");   // tile t landed; t+1 in flight
    } else {
      asm volatile("s_waitcnt vmcnt(0)" ::: "memory");
    }
    __builtin_amdgcn_sched_barrier(0);
    __builtin_amdgcn_s_barrier();    // all waves' tile-t loads landed

    bf16x8 af[4], bfv[4];
#pragma unroll
    for (int mi = 0; mi < 4; ++mi) {
      const float4 v0 = *(const float4*)(lds + cur + abase[mi]);
      const float4 v1 = *(const float4*)(lds + cur + (abase[mi] ^ 16));
      af[mi] = cvt8(v0, v1);
    }
#pragma unroll
    for (int ni = 0; ni < 4; ++ni)
      bfv[ni] = *(const bf16x8*)(lds + cur + bbase[ni]);
#pragma unroll
    for (int mi = 0; mi < 4; ++mi)
#pragma unroll
      for (int ni = 0; ni < 4; ++ni)
        acc[mi][ni] = MFMA16(af[mi], bfv[ni], acc[mi][ni]);
    __builtin_amdgcn_sched_barrier(0);
    __builtin_amdgcn_s_barrier();    // reads of buf[cur] done before re-stage
  }

  // epilogue: C/D layout col = lane&15, row = (lane>>4)*4 + r  [m89-verified]
#pragma unroll
  for (int mi = 0; mi < 4; ++mi) {
    const int mb = m0 + mi * 16 + hi * 4;   // 4-aligned; M % 4 == 0
    if (mb >= M) continue;
#pragma unroll
    for (int ni = 0; ni < 4; ++ni) {
      const int n = w * 64 + ni * 16 + lo;
      const float bia = bias[n];
      if (mode == 0) {
#pragma unroll
        for (int rr = 0; rr < 4; ++rr)
          qb[(size_t)(mb + rr) * 256 + n] = (bf16_t)((acc[mi][ni][rr] + bia) * qscale);
      } else if (mode == 1) {
        const int b = mb / 4000, t = mb - b * 4000;
#pragma unroll
        for (int rr = 0; rr < 4; ++rr)
          kb[((size_t)b * 4064 + t + 50 + rr) * 256 + n] = (bf16_t)(acc[mi][ni][rr] + bia);
      } else {
        const int b = mb / 4000, t = mb - b * 4000;
        const int h = n >> 5, dv = n & 31;
        bf16_t* O = vt + ((size_t)((b * 8 + h) * 32 + dv)) * 4064 + t + 50;
        unsigned short e0 = bbits((bf16_t)(acc[mi][ni][0] + bia));
        unsigned short e1 = bbits((bf16_t)(acc[mi][ni][1] + bia));
        unsigned short e2 = bbits((bf16_t)(acc[mi][ni][2] + bia));
        unsigned short e3 = bbits((bf16_t)(acc[mi][ni][3] + bia));
        unsigned* O32 = (unsigned*)O;       // (t+50) even -> 4B aligned
        O32[0] = (unsigned)e0 | ((unsigned)e1 << 16);
        O32[1] = (unsigned)e2 | ((unsigned)e3 << 16);
      }
    }
  }
}

// ---- output GEMM: ao[M x 256] (bf16) x Wo^T + bo -> fp32 out ----
__global__ __launch_bounds__(256)
void out_gemm(const bf16_t* __restrict__ ao, const bf16_t* __restrict__ wt,
              const float* __restrict__ bias, float* __restrict__ Out, int M) {
  // dbuf: [2] x { A 4KB (256 slots, bf16 linear) + B 16KB }
  __shared__ __align__(16) char lds[2 * 20480];

  const int tid  = threadIdx.x;
  const int lane = tid & 63;
  const int w    = tid >> 6;
  const int lo   = lane & 15, hi = lane >> 4;
  const int m0   = blockIdx.x * 64;

  const bf16_t* asrc;
  int aoff;
  {
    const int s = w * 64 + lane;
    const int row = s >> 2;
    const int ar = (m0 + row < M) ? (m0 + row) : (M - 1);
    asrc = ao + (size_t)ar * 256 + ((s & 3) << 3);
    aoff = w * 1024;
  }
  const bf16_t* bsrc[4];
  int boff[4];
#pragma unroll
  for (int j = 0; j < 4; ++j) {
    const int s = (w * 4 + j) * 64 + lane;
    bsrc[j] = wt + (size_t)(s >> 2) * 256 + ((s & 3) << 3);
    boff[j] = 4096 + (w * 4 + j) * 1024;
  }
  int abase[4], bbase[4];
#pragma unroll
  for (int mi = 0; mi < 4; ++mi)
    abase[mi] = (mi * 16 + lo) * 64 + hi * 16;
#pragma unroll
  for (int ni = 0; ni < 4; ++ni)
    bbase[ni] = 4096 + (w * 64 + ni * 16 + lo) * 64 + hi * 16;

  f32x4 acc[4][4] = {};

  gload16(asrc, lds + aoff);
#pragma unroll
  for (int j = 0; j < 4; ++j) gload16(bsrc[j], lds + boff[j]);

  for (int t = 0; t < 8; ++t) {
    const int cur = (t & 1) * 20480;
    if (t < 7) {
      const int nxt = ((t + 1) & 1) * 20480;
      gload16(asrc + (t + 1) * 32, lds + nxt + aoff);
#pragma unroll
      for (int j = 0; j < 4; ++j) gload16(bsrc[j] + (t + 1) * 32, lds + nxt + boff[j]);
      asm volatile("s_waitcnt vmcnt(5)" ::: "memory");
    } else {
      asm volatile("s_waitcnt vmcnt(0)" ::: "memory");
    }
    __builtin_amdgcn_sched_barrier(0);
    __builtin_amdgcn_s_barrier();

    bf16x8 af[4], bfv[4];
#pragma unroll
    for (int mi = 0; mi < 4; ++mi)
      af[mi] = *(const bf16x8*)(lds + cur + abase[mi]);
#pragma unroll
    for (int ni = 0; ni < 4; ++ni)
      bfv[ni] = *(const bf16x8*)(lds + cur + bbase[ni]);
#pragma unroll
    for (int mi = 0; mi < 4; ++mi)
#pragma unroll
      for (int ni = 0; ni < 4; ++ni)
        acc[mi][ni] = MFMA16(af[mi], bfv[ni], acc[mi][ni]);
    __builtin_amdgcn_sched_barrier(0);
    __builtin_amdgcn_s_barrier();
  }

#pragma unroll
  for (int mi = 0; mi < 4; ++mi) {
    const int mb = m0 + mi * 16 + hi * 4;
    if (mb >= M) continue;
#pragma unroll
    for (int ni = 0; ni < 4; ++ni) {
      const int n = w * 64 + ni * 16 + lo;
      const float bia = bias[n];
#pragma unroll
      for (int rr = 0; rr < 4; ++rr)
        Out[(size_t)(mb + rr) * 256 + n] = acc[mi][ni][rr] + bia;
    }
  }
}

// ---- fill replicate-pad edges + zero tails for kb and vt (nb batches) ----
__global__ void fill_edges(bf16_t* __restrict__ kb, bf16_t* __restrict__ vt, int nb) {
  const int idx = blockIdx.x * 256 + threadIdx.x;
  const int kcnt = nb * 64 * 256;
  if (idx < kcnt) {                    // kb: [nb][4064][256]
    const int b  = idx >> 14;
    const int pp = (idx >> 8) & 63;    // 0..63
    const int nn = idx & 255;
    const int p  = (pp < 50) ? pp : pp + 4000;   // [0,50) and [4050,4064)
    bf16_t v = (pp < 50) ? kb[((size_t)b * 4064 + 50) * 256 + nn] : (bf16_t)0.f;
    kb[((size_t)b * 4064 + p) * 256 + nn] = v;
  } else {                             // vt: [nb*8][32][4064]
    const int j  = idx - kcnt;
    const int bh = j >> 11;
    const int dv = (j >> 6) & 31;
    const int pp = j & 63;
    const int p  = (pp < 50) ? pp : pp + 4000;
    bf16_t v = (pp < 50) ? vt[((size_t)bh * 32 + dv) * 4064 + 50] : (bf16_t)0.f;
    vt[((size_t)bh * 32 + dv) * 4064 + p] = v;
  }
}

// ---- windowed attention: one block per (b',h,window), 7 waves = 7 row-strips ----
// Chunked: per 32-col chunk {2x QK MFMA -> exp -> 16x32 LDS bounce -> PV 3 MFMA}.
// No cross-lane ops, no barriers; denom via E@ones; normalize after PV.
__global__ __launch_bounds__(448)
void attn_win(const bf16_t* __restrict__ qb, const bf16_t* __restrict__ kb,
              const bf16_t* __restrict__ vt, bf16_t* __restrict__ ao) {
  const int blk = blockIdx.x;
  const int n = blk % 40;
  const int h = (blk / 40) & 7;
  const int b = blk / 320;
  const int wv = threadIdx.x >> 6;     // strip 0..6, rows i in [50+16wv, 66+16wv)
  const int lane = threadIdx.x & 63;
  const int lo = lane & 15, hi = lane >> 4;

  __shared__ __align__(16) bf16_t E[7][16][40];  // per-wave 16x32 chunk (pad 40)

  const int i0 = 50 + 16 * wv;
  int jtmax = (65 + 16 * wv) >> 4;     // last 16-tile with any unmasked element
  if (jtmax > 9) jtmax = 9;
  const int reach = jtmax * 16 + 16;

  // Q fragment (pre-scaled by 1/sqrt(200)): row lo -> token t = n*100+16wv+lo
  int tq = n * 100 + 16 * wv + lo;
  if (tq > 3999) tq = 3999;            // rows i>=150 are discarded at store
  const bf16x8 qf = *(const bf16x8*)&qb[((size_t)b * 4000 + tq) * 256 + h * 32 + hi * 8];

  const f32x4 zero = {0.f, 0.f, 0.f, 0.f};
  bf16x8 onesf;
#pragma unroll
  for (int u = 0; u < 8; ++u) onesf[u] = (bf16_t)1.0f;

  f32x4 o0 = zero, o1 = zero, sm = zero;
  const size_t vbase = ((size_t)((b * 8 + h) * 32)) * 4064 + n * 100;
  const size_t kbase = ((size_t)(b * 4064 + n * 100)) * 256 + h * 32 + hi * 8;
  const int dbase = i0 + hi * 4 - lo;  // d = dbase + r - 16*jt

#pragma unroll
  for (int kt = 0; kt < 5; ++kt) if (kt * 32 < reach) {
    // two score tiles -> E chunk [16][32]
#pragma unroll
    for (int half = 0; half < 2; ++half) {
      const int jt = kt * 2 + half;
      if (jt <= jtmax) {
        const bf16x8 kf = *(const bf16x8*)&kb[kbase + (size_t)(jt * 16 + lo) * 256];
        const f32x4 s = MFMA16(qf, kf, zero);
#pragma unroll
        for (int r = 0; r < 4; ++r) {
          const int d = dbase + r - jt * 16;
          const float df = (float)d;
          float c = __builtin_amdgcn_rcpf(__builtin_fmaf(0.25f * df, df, 1.f));
          c = (d == 0) ? 0.f : c;      // eye-mask: diagonal score -> 0 -> e=1
          float e = __expf(s[r] * c);
          e = (d < 0) ? 0.f : e;       // causal mask
          E[wv][hi * 4 + r][half * 16 + lo] = (bf16_t)e;
        }
      } else {
#pragma unroll
        for (int r = 0; r < 4; ++r)
          E[wv][hi * 4 + r][half * 16 + lo] = (bf16_t)0.f;
      }
    }
    // PV + denom for this 32-col chunk (wave-private LDS, in-order DS)
    const bf16x8 pf = *(const bf16x8*)&E[wv][lo][hi * 8];
    const bf16x8 v0 = *(const bf16x8*)&vt[vbase + (size_t)lo * 4064 + kt * 32 + hi * 8];
    const bf16x8 v1 = *(const bf16x8*)&vt[vbase + (size_t)(16 + lo) * 4064 + kt * 32 + hi * 8];
    o0 = MFMA16(pf, v0, o0);
    o1 = MFMA16(pf, v1, o1);
    sm = MFMA16(pf, onesf, sm);
  }

  // store central rows (i in [50,150)): out = o * rcp(rowsum); rowsum >= 1
#pragma unroll
  for (int r = 0; r < 4; ++r) {
    const int i = i0 + hi * 4 + r;
    if (i < 150) {
      const float ri = __builtin_amdgcn_rcpf(sm[r]);
      const int t = n * 100 + i - 50;
      bf16_t* op = &ao[((size_t)b * 4000 + t) * 256 + h * 32];
      op[lo]      = (bf16_t)(o0[r] * ri);
      op[16 + lo] = (bf16_t)(o1[r] * ri);
    }
  }
}

// ---------------------------------------------------------------------------
extern "C" void kernel_launch(void* const* d_in, const int* in_sizes, int n_in,
                              void* d_out, int out_size, void* d_ws, size_t ws_size,
                              hipStream_t stream) {
  (void)in_sizes; (void)n_in; (void)out_size;
  const float* query = (const float*)d_in[0];
  const float* key   = (const float*)d_in[1];
  const float* value = (const float*)d_in[2];
  const float* Wq = (const float*)d_in[3];
  const float* bq = (const float*)d_in[4];
  const float* Wk = (const float*)d_in[5];
  const float* bk = (const float*)d_in[6];
  const float* Wv = (const float*)d_in[7];
  const float* bv = (const float*)d_in[8];
  const float* Wo = (const float*)d_in[9];
  const float* bo = (const float*)d_in[10];

  // batch chunk (ws is large enough for bc=8 in practice)
  int bc = 8;
  while (bc > 1 && 524288ull + (unsigned long long)bc * 8257536ull > (unsigned long long)ws_size)
    bc >>= 1;

  bf16_t* wt = (bf16_t*)d_ws;                           // 4 * 65536
  bf16_t* qb = wt + 4 * 65536;                          // bc*4000*256
  bf16_t* kb = qb + (size_t)bc * 4000 * 256;            // bc*4064*256
  bf16_t* vt = kb + (size_t)bc * 4064 * 256;            // bc*8*32*4064
  bf16_t* ao = vt + (size_t)bc * 8 * 32 * 4064;         // bc*4000*256

  prep_weights<<<256, 256, 0, stream>>>(Wq, Wk, Wv, Wo, wt);

  const float qscale = 0.07071067811865475f;  // 1/sqrt(200) folded into qb

  for (int b0 = 0; b0 < 8; b0 += bc) {
    const int M = bc * 4000;
    const int mblk = (M + 63) / 64;
    const float* qx = query + (size_t)b0 * 4000 * 256;
    const float* kx = key   + (size_t)b0 * 4000 * 256;
    const float* vx = value + (size_t)b0 * 4000 * 256;
    float* ox = (float*)d_out + (size_t)b0 * 4000 * 256;

    proj_gemm<<<dim3(mblk, 3), 256, 0, stream>>>(qx, kx, vx, wt, bq, bk, bv,
                                                 qb, kb, vt, M, qscale);
    fill_edges<<<bc * 128, 256, 0, stream>>>(kb, vt, bc);
    attn_win<<<bc * 320, 448, 0, stream>>>(qb, kb, vt, ao);
    out_gemm<<<dim3(mblk), 256, 0, stream>>>(ao, wt + 3 * 65536, bo, ox, M);
  }
}